// Round 1
// baseline (1514.776 us; speedup 1.0000x reference)
//
#include <hip/hip_runtime.h>
#include <math.h>

#define N_NODES  100000
#define N_EDGES  3200000
#define N_GRAPHS 1024

// ---------------- K1: deg=1 (self loop), bufA = x @ W1 ----------------
__global__ void k_init(const float* __restrict__ x, const float* __restrict__ W1,
                       int* __restrict__ deg, float* __restrict__ bufA) {
    int i = blockIdx.x * blockDim.x + threadIdx.x;
    if (i >= N_NODES) return;
    deg[i] = 1;
    float x0 = x[i * 3 + 0], x1 = x[i * 3 + 1], x2 = x[i * 3 + 2];
#pragma unroll
    for (int j = 0; j < 16; j++) {
        bufA[i * 16 + j] = x0 * W1[j] + x1 * W1[16 + j] + x2 * W1[32 + j];
    }
}

// ---------------- K2: in-degree over targets ----------------
__global__ void k_deg(const int* __restrict__ col, int* __restrict__ deg) {
    int e = blockIdx.x * blockDim.x + threadIdx.x;
    if (e >= N_EDGES) return;
    atomicAdd(&deg[col[e]], 1);
}

// ---------------- K3: dinv = rsqrt(deg); bufB = bufA * dinv^2 (self loop init) ----
__global__ void k_dinv_self(int* __restrict__ deg_in, float* __restrict__ dinv,
                            const float* __restrict__ bufA, float* __restrict__ bufB) {
    int i = blockIdx.x * blockDim.x + threadIdx.x;
    if (i >= N_NODES) return;
    float d = rsqrtf((float)deg_in[i]);
    dinv[i] = d;          // same buffer as deg_in (reinterpreted) — per-thread RMW, safe
    float s = d * d;
#pragma unroll
    for (int j = 0; j < 16; j++) bufB[i * 16 + j] = bufA[i * 16 + j] * s;
}

// ---------------- K4/K6: edge scatter: bufB[col] += bufA[row]*norm ----------------
// 4 threads per edge, each owns a float4 slice of the 16-wide feature row.
__global__ void k_msg(const int* __restrict__ row, const int* __restrict__ col,
                      const float* __restrict__ dinv,
                      const float* __restrict__ src, float* __restrict__ dst) {
    long long t = (long long)blockIdx.x * blockDim.x + threadIdx.x;
    if (t >= (long long)N_EDGES * 4) return;
    int e = (int)(t >> 2);
    int p = (int)(t & 3);
    int r = row[e], c = col[e];
    float nrm = dinv[r] * dinv[c];
    float4 v = ((const float4*)(src + (long long)r * 16))[p];
    float* d = dst + (long long)c * 16 + p * 4;
    atomicAdd(d + 0, v.x * nrm);
    atomicAdd(d + 1, v.y * nrm);
    atomicAdd(d + 2, v.z * nrm);
    atomicAdd(d + 3, v.w * nrm);
}

// ---------------- K5: h1 = relu(agg1 + b1); bufA = h1 @ W2; bufB = bufA*dinv^2 ----
__global__ void k_layer2(const float* __restrict__ b1, const float* __restrict__ W2,
                         const float* __restrict__ dinv,
                         float* __restrict__ bufA, float* __restrict__ bufB) {
    __shared__ float sW[256];
    __shared__ float sB[16];
    int tid = threadIdx.x;
    if (tid < 256) sW[tid] = W2[tid];
    if (tid < 16) sB[tid] = b1[tid];
    __syncthreads();
    int i = blockIdx.x * blockDim.x + tid;
    if (i >= N_NODES) return;
    float h[16];
#pragma unroll
    for (int k = 0; k < 16; k++) {
        float v = bufB[i * 16 + k] + sB[k];
        h[k] = v > 0.f ? v : 0.f;
    }
    float s = dinv[i] * dinv[i];
#pragma unroll
    for (int j = 0; j < 16; j++) {
        float acc = 0.f;
#pragma unroll
        for (int k = 0; k < 16; k++) acc += h[k] * sW[k * 16 + j];
        bufA[i * 16 + j] = acc;
        bufB[i * 16 + j] = acc * s;
    }
}

// ---------------- K7: pool per graph + head + log_softmax ----------------
__global__ void k_pool_head(const float* __restrict__ agg2, const int* __restrict__ batch,
                            const float* __restrict__ b2, const float* __restrict__ Wl,
                            const float* __restrict__ bl, float* __restrict__ out) {
    int g = blockIdx.x;
    int t = threadIdx.x;  // 64 threads = 1 wave
    __shared__ int range[2];
    __shared__ float part[64];
    __shared__ float pooled[16];
    __shared__ float logits[7];
    if (t < 2) {
        int target = g + t;
        int lo = 0, hi = N_NODES;
        while (lo < hi) {
            int mid = (lo + hi) >> 1;
            if (batch[mid] < target) lo = mid + 1; else hi = mid;
        }
        range[t] = lo;
    }
    __syncthreads();
    int s = range[0], e = range[1];
    int f = t & 15, chunk = t >> 4;  // 4 node-chunks x 16 features
    float acc = 0.f;
    for (int i = s + chunk; i < e; i += 4) acc += agg2[(long long)i * 16 + f];
    part[t] = acc;
    __syncthreads();
    if (t < 16) {
        float p = part[t] + part[t + 16] + part[t + 32] + part[t + 48];
        pooled[t] = p + (float)(e - s) * b2[t];  // layer-2 bias folded in per node
    }
    __syncthreads();
    if (t < 7) {
        float a = bl[t];
#pragma unroll
        for (int k = 0; k < 16; k++) a += pooled[k] * Wl[k * 7 + t];
        logits[t] = a;
    }
    __syncthreads();
    if (t == 0) {
        float m = logits[0];
#pragma unroll
        for (int c = 1; c < 7; c++) m = fmaxf(m, logits[c]);
        float sum = 0.f;
#pragma unroll
        for (int c = 0; c < 7; c++) sum += expf(logits[c] - m);
        float lse = logf(sum) + m;
#pragma unroll
        for (int c = 0; c < 7; c++) out[g * 7 + c] = logits[c] - lse;
    }
}

extern "C" void kernel_launch(void* const* d_in, const int* in_sizes, int n_in,
                              void* d_out, int out_size, void* d_ws, size_t ws_size,
                              hipStream_t stream) {
    const float* x    = (const float*)d_in[0];
    const int*   ei   = (const int*)d_in[1];   // [2, E] flattened
    const int*   batch= (const int*)d_in[2];
    const float* W1   = (const float*)d_in[3];
    const float* b1   = (const float*)d_in[4];
    const float* W2   = (const float*)d_in[5];
    const float* b2   = (const float*)d_in[6];
    const float* Wl   = (const float*)d_in[7];
    const float* bl   = (const float*)d_in[8];
    float* out = (float*)d_out;

    const int* row = ei;             // edge_index[0] = sources
    const int* col = ei + N_EDGES;   // edge_index[1] = targets

    float* ws = (float*)d_ws;
    float* dinv = ws;                          // N floats (doubles as int deg)
    int*   deg  = (int*)ws;
    float* bufA = ws + N_NODES;                // N*16
    float* bufB = ws + N_NODES + N_NODES * 16; // N*16

    const int BT = 256;
    int nodeBlocks = (N_NODES + BT - 1) / BT;
    int edgeBlocks = (N_EDGES + BT - 1) / BT;
    long long msgThreads = (long long)N_EDGES * 4;
    int msgBlocks = (int)((msgThreads + BT - 1) / BT);

    k_init<<<nodeBlocks, BT, 0, stream>>>(x, W1, deg, bufA);
    k_deg<<<edgeBlocks, BT, 0, stream>>>(col, deg);
    k_dinv_self<<<nodeBlocks, BT, 0, stream>>>(deg, dinv, bufA, bufB);
    k_msg<<<msgBlocks, BT, 0, stream>>>(row, col, dinv, bufA, bufB);
    k_layer2<<<nodeBlocks, BT, 0, stream>>>(b1, W2, dinv, bufA, bufB);
    k_msg<<<msgBlocks, BT, 0, stream>>>(row, col, dinv, bufA, bufB);
    k_pool_head<<<N_GRAPHS, 64, 0, stream>>>(bufB, batch, b2, Wl, bl, out);
}

// Round 2
// 648.142 us; speedup vs baseline: 2.3371x; 2.3371x over previous
//
#include <hip/hip_runtime.h>
#include <math.h>

#define N_NODES  100000
#define N_EDGES  3200000
#define N_GRAPHS 1024
#define NB_NODE  391   /* ceil(100000/256) */

// ---- K1: cnt zeroed by memset; deg count over targets ----
__global__ void k_deg(const int* __restrict__ col, int* __restrict__ cnt) {
    int e = blockIdx.x * blockDim.x + threadIdx.x;
    if (e >= N_EDGES) return;
    atomicAdd(&cnt[col[e]], 1);
}

// ---- K2: dinv = rsqrt(cnt+1); bufA = (x@W1) * dinv  (pre-scaled source rows) ----
__global__ void k_dinv_xw1(const int* __restrict__ cnt, float* __restrict__ dinv,
                           const float* __restrict__ x, const float* __restrict__ W1,
                           float* __restrict__ bufA) {
    int i = blockIdx.x * blockDim.x + threadIdx.x;
    if (i >= N_NODES) return;
    float d = rsqrtf((float)(cnt[i] + 1));  // +1 self loop
    dinv[i] = d;
    float x0 = x[i * 3 + 0], x1 = x[i * 3 + 1], x2 = x[i * 3 + 2];
#pragma unroll
    for (int j = 0; j < 16; j++)
        bufA[i * 16 + j] = (x0 * W1[j] + x1 * W1[16 + j] + x2 * W1[32 + j]) * d;
}

// ---- Scan step A: per-block sums of cnt ----
__global__ void k_blocksum(const int* __restrict__ cnt, int* __restrict__ part) {
    __shared__ int s[256];
    int t = threadIdx.x;
    int i = blockIdx.x * 256 + t;
    s[t] = (i < N_NODES) ? cnt[i] : 0;
    __syncthreads();
    for (int o = 128; o > 0; o >>= 1) {
        if (t < o) s[t] += s[t + o];
        __syncthreads();
    }
    if (t == 0) part[blockIdx.x] = s[0];
}

// ---- Scan step B: exclusive scan of the 391 partials (one block) ----
__global__ void k_scanpart(int* __restrict__ part) {
    __shared__ int s[512];
    int t = threadIdx.x;
    int v0 = (t < NB_NODE) ? part[t] : 0;
    s[t] = v0;
    __syncthreads();
    for (int o = 1; o < 512; o <<= 1) {
        int v = (t >= o) ? s[t - o] : 0;
        __syncthreads();
        s[t] += v;
        __syncthreads();
    }
    if (t < NB_NODE) part[t] = s[t] - v0;  // exclusive
}

// ---- Scan step C: full exclusive scan -> rowptr, cursor ----
__global__ void k_scanwrite(const int* __restrict__ cnt, const int* __restrict__ part,
                            int* __restrict__ rowptr, int* __restrict__ cursor) {
    __shared__ int s[256];
    int t = threadIdx.x;
    int i = blockIdx.x * 256 + t;
    int v = (i < N_NODES) ? cnt[i] : 0;
    s[t] = v;
    __syncthreads();
    for (int o = 1; o < 256; o <<= 1) {
        int u = (t >= o) ? s[t - o] : 0;
        __syncthreads();
        s[t] += u;
        __syncthreads();
    }
    int excl = s[t] - v + part[blockIdx.x];
    if (i < N_NODES) {
        rowptr[i] = excl;
        cursor[i] = excl;
        if (i == N_NODES - 1) rowptr[N_NODES] = excl + v;
    }
}

// ---- K3: scatter edges into CSR slots (int atomics only, once) ----
__global__ void k_scatter(const int* __restrict__ row, const int* __restrict__ col,
                          int* __restrict__ cursor, int* __restrict__ csr) {
    int e = blockIdx.x * blockDim.x + threadIdx.x;
    if (e >= N_EDGES) return;
    int c = col[e];
    int pos = atomicAdd(&cursor[c], 1);
    csr[pos] = row[e];
}

// ---- K4/K6: gather: dst[i] = dinv[i] * (src[i] + sum_{s in N(i)} src[s]) ----
// src rows pre-scaled by dinv[src]. 4 lanes per node, float4 each -> 64B coalesced row.
__global__ void k_gather(const float4* __restrict__ src, const int* __restrict__ csr,
                         const int* __restrict__ rowptr, const float* __restrict__ dinv,
                         float4* __restrict__ dst) {
    int tid = threadIdx.x;
    int node = blockIdx.x * 64 + (tid >> 2);
    int f = tid & 3;
    if (node >= N_NODES) return;
    int s = rowptr[node], e = rowptr[node + 1];
    float4 acc = src[node * 4 + f];  // self-loop term (pre-scaled)
    for (int j = s; j < e; j++) {
        int si = csr[j];
        float4 v = src[si * 4 + f];
        acc.x += v.x; acc.y += v.y; acc.z += v.z; acc.w += v.w;
    }
    float d = dinv[node];
    acc.x *= d; acc.y *= d; acc.z *= d; acc.w *= d;
    dst[node * 4 + f] = acc;
}

// ---- K5: h1 = relu(agg1 + b1); bufA = (h1 @ W2) * dinv ----
__global__ void k_layer2(const float* __restrict__ b1, const float* __restrict__ W2,
                         const float* __restrict__ dinv,
                         float* __restrict__ bufA, const float* __restrict__ bufB) {
    __shared__ float sW[256];
    __shared__ float sB[16];
    int tid = threadIdx.x;
    if (tid < 256) sW[tid] = W2[tid];
    if (tid < 16) sB[tid] = b1[tid];
    __syncthreads();
    int i = blockIdx.x * blockDim.x + tid;
    if (i >= N_NODES) return;
    float h[16];
#pragma unroll
    for (int k = 0; k < 16; k++) {
        float v = bufB[i * 16 + k] + sB[k];
        h[k] = v > 0.f ? v : 0.f;
    }
    float d = dinv[i];
#pragma unroll
    for (int j = 0; j < 16; j++) {
        float acc = 0.f;
#pragma unroll
        for (int k = 0; k < 16; k++) acc += h[k] * sW[k * 16 + j];
        bufA[i * 16 + j] = acc * d;
    }
}

// ---- K7: pool per graph + head + log_softmax ----
__global__ void k_pool_head(const float* __restrict__ agg2, const int* __restrict__ batch,
                            const float* __restrict__ b2, const float* __restrict__ Wl,
                            const float* __restrict__ bl, float* __restrict__ out) {
    int g = blockIdx.x;
    int t = threadIdx.x;  // 64 threads = 1 wave
    __shared__ int range[2];
    __shared__ float part[64];
    __shared__ float pooled[16];
    __shared__ float logits[7];
    if (t < 2) {
        int target = g + t;
        int lo = 0, hi = N_NODES;
        while (lo < hi) {
            int mid = (lo + hi) >> 1;
            if (batch[mid] < target) lo = mid + 1; else hi = mid;
        }
        range[t] = lo;
    }
    __syncthreads();
    int s = range[0], e = range[1];
    int f = t & 15, chunk = t >> 4;
    float acc = 0.f;
    for (int i = s + chunk; i < e; i += 4) acc += agg2[(long long)i * 16 + f];
    part[t] = acc;
    __syncthreads();
    if (t < 16) {
        float p = part[t] + part[t + 16] + part[t + 32] + part[t + 48];
        pooled[t] = p + (float)(e - s) * b2[t];
    }
    __syncthreads();
    if (t < 7) {
        float a = bl[t];
#pragma unroll
        for (int k = 0; k < 16; k++) a += pooled[k] * Wl[k * 7 + t];
        logits[t] = a;
    }
    __syncthreads();
    if (t == 0) {
        float m = logits[0];
#pragma unroll
        for (int c = 1; c < 7; c++) m = fmaxf(m, logits[c]);
        float sum = 0.f;
#pragma unroll
        for (int c = 0; c < 7; c++) sum += expf(logits[c] - m);
        float lse = logf(sum) + m;
#pragma unroll
        for (int c = 0; c < 7; c++) out[g * 7 + c] = logits[c] - lse;
    }
}

extern "C" void kernel_launch(void* const* d_in, const int* in_sizes, int n_in,
                              void* d_out, int out_size, void* d_ws, size_t ws_size,
                              hipStream_t stream) {
    const float* x     = (const float*)d_in[0];
    const int*   ei    = (const int*)d_in[1];
    const int*   batch = (const int*)d_in[2];
    const float* W1    = (const float*)d_in[3];
    const float* b1    = (const float*)d_in[4];
    const float* W2    = (const float*)d_in[5];
    const float* b2    = (const float*)d_in[6];
    const float* Wl    = (const float*)d_in[7];
    const float* bl    = (const float*)d_in[8];
    float* out = (float*)d_out;

    const int* row = ei;            // sources
    const int* col = ei + N_EDGES;  // targets

    // ws layout (units: 4-byte words). bufA/bufB offsets are multiples of 4 (float4-aligned).
    int*   cnt    = (int*)d_ws;                 // 100000
    float* dinv   = (float*)d_ws + 100000;      // 100000
    int*   rowptr = (int*)d_ws + 200000;        // 100001
    int*   cursor = (int*)d_ws + 300004;        // 100000
    int*   part   = (int*)d_ws + 400004;        // 512
    int*   csr    = (int*)d_ws + 400516;        // 3200000
    float* bufA   = (float*)d_ws + 3600516;     // 1600000 (offset %4==0)
    float* bufB   = (float*)d_ws + 5200516;     // 1600000 (offset %4==0)

    const int BT = 256;
    int edgeBlocks = (N_EDGES + BT - 1) / BT;
    int gatherBlocks = (N_NODES + 63) / 64;

    hipMemsetAsync(cnt, 0, N_NODES * sizeof(int), stream);
    k_deg<<<edgeBlocks, BT, 0, stream>>>(col, cnt);
    k_dinv_xw1<<<NB_NODE, BT, 0, stream>>>(cnt, dinv, x, W1, bufA);
    k_blocksum<<<NB_NODE, BT, 0, stream>>>(cnt, part);
    k_scanpart<<<1, 512, 0, stream>>>(part);
    k_scanwrite<<<NB_NODE, BT, 0, stream>>>(cnt, part, rowptr, cursor);
    k_scatter<<<edgeBlocks, BT, 0, stream>>>(row, col, cursor, csr);
    k_gather<<<gatherBlocks, BT, 0, stream>>>((const float4*)bufA, csr, rowptr, dinv, (float4*)bufB);
    k_layer2<<<NB_NODE, BT, 0, stream>>>(b1, W2, dinv, bufA, bufB);
    k_gather<<<gatherBlocks, BT, 0, stream>>>((const float4*)bufA, csr, rowptr, dinv, (float4*)bufB);
    k_pool_head<<<N_GRAPHS, 64, 0, stream>>>(bufB, batch, b2, Wl, bl, out);
}

// Round 3
// 333.904 us; speedup vs baseline: 4.5366x; 1.9411x over previous
//
#include <hip/hip_runtime.h>
#include <math.h>

#define N_NODES  100000
#define N_EDGES  3200000
#define N_GRAPHS 1024
#define NB_NODE  391          /* ceil(100000/256) node blocks */
#define NBUCK    391          /* buckets of 256 nodes */
#define EPB      8192         /* edges per block in pair scatter */
#define NPB      391          /* pair-scatter blocks = ceil(E/EPB) */

// ---- KC: bucket counts, LDS-aggregated ----
__global__ void k_bucket_count(const int* __restrict__ col, int* __restrict__ gcount) {
    __shared__ int lc[NBUCK];
    int t = threadIdx.x;
    for (int j = t; j < NBUCK; j += 256) lc[j] = 0;
    __syncthreads();
    int stride = gridDim.x * 256;
    for (int e = blockIdx.x * 256 + t; e < N_EDGES; e += stride)
        atomicAdd(&lc[col[e] >> 8], 1);
    __syncthreads();
    for (int j = t; j < NBUCK; j += 256)
        if (lc[j]) atomicAdd(&gcount[j], lc[j]);
}

// ---- KS: scan bucket counts -> gbase (exclusive), init gcursor, rowptr[N]=E ----
__global__ void k_bucket_scan(const int* __restrict__ gcount, int* __restrict__ gbase,
                              int* __restrict__ gcursor, int* __restrict__ rowptr) {
    __shared__ int s[512];
    int t = threadIdx.x;
    int v0 = (t < NBUCK) ? gcount[t] : 0;
    s[t] = v0;
    __syncthreads();
    for (int o = 1; o < 512; o <<= 1) {
        int v = (t >= o) ? s[t - o] : 0;
        __syncthreads();
        s[t] += v;
        __syncthreads();
    }
    if (t < NBUCK) {
        int excl = s[t] - v0;
        gbase[t] = excl;
        gcursor[t] = excl;
        if (t == NBUCK - 1) gbase[NBUCK] = excl + v0;  // == N_EDGES
    }
    if (t == 0) rowptr[N_NODES] = N_EDGES;
}

// ---- KP: bucketed pair scatter. pack = r | (c&255)<<17 ----
__global__ void k_pair_scatter(const int* __restrict__ row, const int* __restrict__ col,
                               int* __restrict__ gcursor, int* __restrict__ pairbuf) {
    __shared__ int   sp[EPB];
    __shared__ short sb[EPB];
    __shared__ int   lcnt[NBUCK];
    int t = threadIdx.x;
    int e0 = blockIdx.x * EPB;
    int n = N_EDGES - e0; if (n > EPB) n = EPB;
    for (int j = t; j < NBUCK; j += 256) lcnt[j] = 0;
    __syncthreads();
    for (int k = t; k < n; k += 256) {
        int e = e0 + k;
        int r = row[e], c = col[e];
        sp[k] = r | ((c & 255) << 17);
        short b = (short)(c >> 8);
        sb[k] = b;
        atomicAdd(&lcnt[b], 1);
    }
    __syncthreads();
    // reserve contiguous chunk per bucket; turn lcnt into running cursor
    for (int j = t; j < NBUCK; j += 256) {
        int c = lcnt[j];
        int g = (c > 0) ? atomicAdd(&gcursor[j], c) : 0;
        lcnt[j] = g;
    }
    __syncthreads();
    for (int k = t; k < n; k += 256) {
        int pos = atomicAdd(&lcnt[sb[k]], 1);
        pairbuf[pos] = sp[k];
    }
}

// ---- KF: per-bucket CSR finalize + rowptr + dinv ----
__global__ void k_finalize(const int* __restrict__ pairbuf, const int* __restrict__ gbase,
                           int* __restrict__ rowptr, float* __restrict__ dinv,
                           int* __restrict__ csr) {
    __shared__ int lcnt[256];
    __shared__ int ls[256];
    int t = threadIdx.x;
    int b = blockIdx.x;
    int base = gbase[b];
    int cnt_b = gbase[b + 1] - base;
    int node0 = b << 8;
    int nn = N_NODES - node0; if (nn > 256) nn = 256;
    lcnt[t] = 0;
    __syncthreads();
    for (int k = t; k < cnt_b; k += 256)
        atomicAdd(&lcnt[pairbuf[base + k] >> 17], 1);
    __syncthreads();
    int myc = lcnt[t];
    ls[t] = myc;
    __syncthreads();
    for (int o = 1; o < 256; o <<= 1) {
        int v = (t >= o) ? ls[t - o] : 0;
        __syncthreads();
        ls[t] += v;
        __syncthreads();
    }
    int excl = ls[t] - myc;
    if (t < nn) {
        rowptr[node0 + t] = base + excl;
        dinv[node0 + t] = rsqrtf((float)(myc + 1));  // +1 self loop
    }
    __syncthreads();
    lcnt[t] = base + excl;  // global write cursor per node
    __syncthreads();
    for (int k = t; k < cnt_b; k += 256) {
        int p = pairbuf[base + k];
        int pos = atomicAdd(&lcnt[p >> 17], 1);
        csr[pos] = p & 0x1FFFF;
    }
}

// ---- K2: bufA = (x@W1) * dinv  (pre-scaled source rows) ----
__global__ void k_xw1(const float* __restrict__ dinv, const float* __restrict__ x,
                      const float* __restrict__ W1, float* __restrict__ bufA) {
    int i = blockIdx.x * blockDim.x + threadIdx.x;
    if (i >= N_NODES) return;
    float d = dinv[i];
    float x0 = x[i * 3 + 0], x1 = x[i * 3 + 1], x2 = x[i * 3 + 2];
#pragma unroll
    for (int j = 0; j < 16; j++)
        bufA[i * 16 + j] = (x0 * W1[j] + x1 * W1[16 + j] + x2 * W1[32 + j]) * d;
}

// ---- gather: dst[i] = dinv[i] * (src[i] + sum_{s in N(i)} src[s]) ----
__global__ void k_gather(const float4* __restrict__ src, const int* __restrict__ csr,
                         const int* __restrict__ rowptr, const float* __restrict__ dinv,
                         float4* __restrict__ dst) {
    int tid = threadIdx.x;
    int node = blockIdx.x * 64 + (tid >> 2);
    int f = tid & 3;
    if (node >= N_NODES) return;
    int s = rowptr[node], e = rowptr[node + 1];
    float4 acc = src[node * 4 + f];  // self-loop term (pre-scaled)
    for (int j = s; j < e; j++) {
        int si = csr[j];
        float4 v = src[si * 4 + f];
        acc.x += v.x; acc.y += v.y; acc.z += v.z; acc.w += v.w;
    }
    float d = dinv[node];
    acc.x *= d; acc.y *= d; acc.z *= d; acc.w *= d;
    dst[node * 4 + f] = acc;
}

// ---- layer2: h1 = relu(agg1 + b1); bufA = (h1 @ W2) * dinv ----
__global__ void k_layer2(const float* __restrict__ b1, const float* __restrict__ W2,
                         const float* __restrict__ dinv,
                         float* __restrict__ bufA, const float* __restrict__ bufB) {
    __shared__ float sW[256];
    __shared__ float sB[16];
    int tid = threadIdx.x;
    if (tid < 256) sW[tid] = W2[tid];
    if (tid < 16) sB[tid] = b1[tid];
    __syncthreads();
    int i = blockIdx.x * blockDim.x + tid;
    if (i >= N_NODES) return;
    float h[16];
#pragma unroll
    for (int k = 0; k < 16; k++) {
        float v = bufB[i * 16 + k] + sB[k];
        h[k] = v > 0.f ? v : 0.f;
    }
    float d = dinv[i];
#pragma unroll
    for (int j = 0; j < 16; j++) {
        float acc = 0.f;
#pragma unroll
        for (int k = 0; k < 16; k++) acc += h[k] * sW[k * 16 + j];
        bufA[i * 16 + j] = acc * d;
    }
}

// ---- pool per graph + head + log_softmax ----
__global__ void k_pool_head(const float* __restrict__ agg2, const int* __restrict__ batch,
                            const float* __restrict__ b2, const float* __restrict__ Wl,
                            const float* __restrict__ bl, float* __restrict__ out) {
    int g = blockIdx.x;
    int t = threadIdx.x;  // 64 threads = 1 wave
    __shared__ int range[2];
    __shared__ float part[64];
    __shared__ float pooled[16];
    __shared__ float logits[7];
    if (t < 2) {
        int target = g + t;
        int lo = 0, hi = N_NODES;
        while (lo < hi) {
            int mid = (lo + hi) >> 1;
            if (batch[mid] < target) lo = mid + 1; else hi = mid;
        }
        range[t] = lo;
    }
    __syncthreads();
    int s = range[0], e = range[1];
    int f = t & 15, chunk = t >> 4;
    float acc = 0.f;
    for (int i = s + chunk; i < e; i += 4) acc += agg2[(long long)i * 16 + f];
    part[t] = acc;
    __syncthreads();
    if (t < 16) {
        float p = part[t] + part[t + 16] + part[t + 32] + part[t + 48];
        pooled[t] = p + (float)(e - s) * b2[t];
    }
    __syncthreads();
    if (t < 7) {
        float a = bl[t];
#pragma unroll
        for (int k = 0; k < 16; k++) a += pooled[k] * Wl[k * 7 + t];
        logits[t] = a;
    }
    __syncthreads();
    if (t == 0) {
        float m = logits[0];
#pragma unroll
        for (int c = 1; c < 7; c++) m = fmaxf(m, logits[c]);
        float sum = 0.f;
#pragma unroll
        for (int c = 0; c < 7; c++) sum += expf(logits[c] - m);
        float lse = logf(sum) + m;
#pragma unroll
        for (int c = 0; c < 7; c++) out[g * 7 + c] = logits[c] - lse;
    }
}

extern "C" void kernel_launch(void* const* d_in, const int* in_sizes, int n_in,
                              void* d_out, int out_size, void* d_ws, size_t ws_size,
                              hipStream_t stream) {
    const float* x     = (const float*)d_in[0];
    const int*   ei    = (const int*)d_in[1];
    const int*   batch = (const int*)d_in[2];
    const float* W1    = (const float*)d_in[3];
    const float* b1    = (const float*)d_in[4];
    const float* W2    = (const float*)d_in[5];
    const float* b2    = (const float*)d_in[6];
    const float* Wl    = (const float*)d_in[7];
    const float* bl    = (const float*)d_in[8];
    float* out = (float*)d_out;

    const int* row = ei;            // sources
    const int* col = ei + N_EDGES;  // targets

    // ws layout (4-byte words); pairbuf aliases bufA+bufB (dead after k_finalize)
    int*   gcount  = (int*)d_ws;                 // @0      392
    int*   gbase   = (int*)d_ws + 400;           // @400    392
    int*   gcursor = (int*)d_ws + 800;           // @800    391
    int*   rowptr  = (int*)d_ws + 1200;          // @1200   100001
    float* dinv    = (float*)d_ws + 101204;      // @101204 100000
    int*   csr     = (int*)d_ws + 201204;        // @201204 3200000
    int*   pairbuf = (int*)d_ws + 3401208;       // @3401208 3200000
    float* bufA    = (float*)d_ws + 3401208;     // alias pairbuf[0..1.6M)
    float* bufB    = (float*)d_ws + 5001208;     // alias pairbuf[1.6M..3.2M)

    const int BT = 256;
    int gatherBlocks = (N_NODES + 63) / 64;

    hipMemsetAsync(gcount, 0, NBUCK * sizeof(int), stream);
    k_bucket_count<<<512, BT, 0, stream>>>(col, gcount);
    k_bucket_scan<<<1, 512, 0, stream>>>(gcount, gbase, gcursor, rowptr);
    k_pair_scatter<<<NPB, BT, 0, stream>>>(row, col, gcursor, pairbuf);
    k_finalize<<<NBUCK, BT, 0, stream>>>(pairbuf, gbase, rowptr, dinv, csr);
    k_xw1<<<NB_NODE, BT, 0, stream>>>(dinv, x, W1, bufA);
    k_gather<<<gatherBlocks, BT, 0, stream>>>((const float4*)bufA, csr, rowptr, dinv, (float4*)bufB);
    k_layer2<<<NB_NODE, BT, 0, stream>>>(b1, W2, dinv, bufA, bufB);
    k_gather<<<gatherBlocks, BT, 0, stream>>>((const float4*)bufA, csr, rowptr, dinv, (float4*)bufB);
    k_pool_head<<<N_GRAPHS, 64, 0, stream>>>(bufB, batch, b2, Wl, bl, out);
}